// Round 3
// baseline (193.261 us; speedup 1.0000x reference)
//
#include <hip/hip_runtime.h>

// DIN encoder. B=8, N=512, D=64, H=64. Two launches:
//   prep   — weight transforms, hq, hk-scatter, X B-frags, enc-X B-frags
//   k2_main— one wave per (b,q), 32 keys/iter, everything through MFMA
#define NB 8
#define NN 512

// ws layout (float offsets)
#define WS_WMF 0        // Wm A-frag-major fp32 [8 slot][64 lane][8]          4096
#define WS_HQ  4096     // hq fp32 [B*N][64]                                262144
#define WS_BF  266240   // B-frags bf16 [B][32 t][4 c][64 lane][8]   (262144 fl)
#define WS_XE  528384   // enc-X bf16 [B][16 c32][4 nt][64 lane][8]  (131072 fl)
// total 659456 floats = 2.64 MB

typedef float fx4 __attribute__((ext_vector_type(4)));
typedef short sx8 __attribute__((ext_vector_type(8)));
typedef int   ix4 __attribute__((ext_vector_type(4)));

static __device__ inline unsigned short f2bf(float f) {
    unsigned u = __float_as_uint(f);
    return (unsigned short)((u + 0x7FFFu + ((u >> 16) & 1u)) >> 16);  // RNE
}

// ---------------- fused prep ----------------
__global__ __launch_bounds__(256) void prep(const float* __restrict__ x,
                                            const float* __restrict__ vm,
                                            const float* __restrict__ W1,
                                            const float* __restrict__ b1,
                                            float* __restrict__ ws) {
    __shared__ float lwq[64 * 65];   // (Wq+Wd)^T  [d][h], pad 65
    __shared__ float lwk[64 * 65];   // (Wk-Wd)^T
    __shared__ float xs[256];
    const int t = threadIdx.x;
    const int blk = blockIdx.x;

    // stage weight combos, coalesced over d
    {
        int d = t & 63, hb = t >> 6;
        #pragma unroll 4
        for (int i = 0; i < 16; ++i) {
            int h = i * 4 + hb;
            float a = W1[h * 256 + d];
            float bb = W1[h * 256 + 64 + d];
            float c = W1[h * 256 + 128 + d];
            lwq[d * 65 + h] = a + c;
            lwk[d * 65 + h] = bb - c;
        }
    }
    const int r0 = blk * 4;
    xs[t] = x[r0 * 64 + t];
    __syncthreads();

    // hq + hk for this block's 4 rows
    {
        int r = t >> 6, h = t & 63;
        const float* xr = xs + r * 64;
        float aq = b1[h], ak = 0.f;
        #pragma unroll
        for (int dd = 0; dd < 64; ++dd) {
            float xv = xr[dd];
            aq = fmaf(xv, lwq[dd * 65 + h], aq);
            ak = fmaf(xv, lwk[dd * 65 + h], ak);
        }
        int row = r0 + r;
        (ws + WS_HQ)[row * 64 + h] = aq;
        // scatter hk into B-frag chunk c=2+(h>>5)
        unsigned short* bfp = (unsigned short*)(ws + WS_BF);
        int bb = row >> 9, k = row & 511;
        int tt = k >> 4, nn = k & 15;
        int c = 2 + (h >> 5);
        int qd = (h >> 3) & 3, j = h & 7;
        int ln = qd * 16 + nn;
        bfp[((((bb * 32 + tt) * 4 + c) * 64 + ln) << 3) + j] = f2bf(ak);
    }

    if (blk < 256) {
        int b = blk >> 5, t5 = blk & 31;
        // X -> BF chunks 0/1
        if (t < 128) {
            unsigned short* bfp = (unsigned short*)(ws + WS_BF);
            int c = t >> 6, L = t & 63;
            int nn = L & 15, qd = L >> 4;
            const float* src = x + ((b * 512 + t5 * 16 + nn) * 64 + c * 32 + qd * 8);
            fx4 v0 = *(const fx4*)src;
            fx4 v1 = *(const fx4*)(src + 4);
            uint4 o;
            o.x = (unsigned)f2bf(v0[0]) | ((unsigned)f2bf(v0[1]) << 16);
            o.y = (unsigned)f2bf(v0[2]) | ((unsigned)f2bf(v0[3]) << 16);
            o.z = (unsigned)f2bf(v1[0]) | ((unsigned)f2bf(v1[1]) << 16);
            o.w = (unsigned)f2bf(v1[2]) | ((unsigned)f2bf(v1[3]) << 16);
            *(uint4*)(bfp + ((((b * 32 + t5) * 4 + c) * 64 + L) << 3)) = o;
        }
        // masked X -> enc B-frags (XE)
        {
            unsigned short* xep = (unsigned short*)(ws + WS_XE);
            int c32 = t5 >> 1, half = t5 & 1;
            int nt = t >> 6, r = t & 63;
            int L = half * 32 + (r & 31);
            int j0 = (r >> 5) * 4;
            int quad = L >> 4, nn = L & 15;
            unsigned short u[4];
            #pragma unroll
            for (int i = 0; i < 4; ++i) {
                int key = c32 * 32 + quad * 8 + j0 + i;
                float v = x[(b * 512 + key) * 64 + nt * 16 + nn] * vm[b * 512 + key];
                u[i] = f2bf(v);
            }
            uint2 o;
            o.x = (unsigned)u[0] | ((unsigned)u[1] << 16);
            o.y = (unsigned)u[2] | ((unsigned)u[3] << 16);
            *(uint2*)(xep + (((((b * 16 + c32) * 4 + nt) * 64 + L) << 3) + j0)) = o;
        }
    } else if (blk < 258) {
        // Wm A-fragment-major
        float* wmf = ws + WS_WMF;
        int e = (blk - 256) * 256 + t;       // 0..511
        int slot = e >> 6, lane = e & 63;
        int ht = slot >> 1, hf = slot & 1;
        int m = lane & 15, qd = lane >> 4;
        int h = ht * 16 + m;
        int dbase = hf * 32 + qd * 8;
        #pragma unroll
        for (int j = 0; j < 8; ++j)
            wmf[e * 8 + j] = W1[h * 256 + 192 + dbase + j];
    }
}

// ---------------- main ----------------
__global__ __launch_bounds__(256, 4) void k2_main(const float* __restrict__ x,
                                                  const float* __restrict__ prelu_a,
                                                  const float* __restrict__ W2,
                                                  const float* __restrict__ b2,
                                                  const float* __restrict__ ws,
                                                  float* __restrict__ out) {
    const int tid  = threadIdx.x;
    const int lane = tid & 63;
    const int wid  = blockIdx.x * 4 + (tid >> 6);
    const int b    = wid >> 9;
    const int rr   = wid & 511;
    const int q    = (rr & 1) ? (511 - (rr >> 1)) : (rr >> 1);  // balance
    const int n    = lane & 15, quad = lane >> 4;
    const int bq   = b * 512 + q;

    const float* wmf = ws + WS_WMF;
    const float* hq  = ws + WS_HQ;
    const unsigned short* bfp = (const unsigned short*)(ws + WS_BF);
    const unsigned short* xep = (const unsigned short*)(ws + WS_XE);

    const float pa  = prelu_a[0];
    const float b2v = b2[0];

    // hq (acc init) and W2 registers: h = ht*16 + quad*4 + r
    float hqr[4][4], w2r[4][4];
    #pragma unroll
    for (int ht = 0; ht < 4; ++ht) {
        fx4 vh = *(const fx4*)(hq + bq * 64 + ht * 16 + quad * 4);
        fx4 vw = *(const fx4*)(W2 + ht * 16 + quad * 4);
        #pragma unroll
        for (int r = 0; r < 4; ++r) { hqr[ht][r] = vh[r]; w2r[ht][r] = vw[r]; }
    }

    // xq for A-frags: lane needs d = half*32 + quad*8 + j
    float xq[2][8];
    {
        const float* xp = x + bq * 64 + quad * 8;
        fx4 t0 = *(const fx4*)xp;
        fx4 t1 = *(const fx4*)(xp + 4);
        fx4 t2 = *(const fx4*)(xp + 32);
        fx4 t3 = *(const fx4*)(xp + 36);
        #pragma unroll
        for (int j = 0; j < 4; ++j) {
            xq[0][j] = t0[j]; xq[0][4 + j] = t1[j];
            xq[1][j] = t2[j]; xq[1][4 + j] = t3[j];
        }
    }

    // A-frags: Wm ⊙ xq (bf16)
    sx8 afrag[4][2];
    #pragma unroll
    for (int ht = 0; ht < 4; ++ht)
        #pragma unroll
        for (int hf = 0; hf < 2; ++hf) {
            const float* wp = wmf + (((ht * 2 + hf) * 64 + lane) << 3);
            fx4 w0 = *(const fx4*)wp;
            fx4 w1 = *(const fx4*)(wp + 4);
            sx8 a;
            #pragma unroll
            for (int j = 0; j < 4; ++j) {
                a[j]     = (short)f2bf(w0[j] * xq[hf][j]);
                a[4 + j] = (short)f2bf(w1[j] * xq[hf][4 + j]);
            }
            afrag[ht][hf] = a;
        }

    // one-hot A-frags for the hk fold
    sx8 oh[4];
    #pragma unroll
    for (int ht = 0; ht < 4; ++ht) {
        sx8 a;
        #pragma unroll
        for (int j = 0; j < 8; ++j) {
            int hp = (ht >> 1) * 32 + quad * 8 + j;
            a[j] = (hp == ht * 16 + n) ? (short)0x3F80 : (short)0;
        }
        oh[ht] = a;
    }

    // score -> A-frag gather constants
    int idxs[8];
    #pragma unroll
    for (int j = 0; j < 8; ++j) idxs[j] = ((quad * 8 + j) & 15) << 2;
    const unsigned sel = (quad < 2) ? 0x05040100u : 0x07060302u;

    fx4 eacc[4];
    #pragma unroll
    for (int nt = 0; nt < 4; ++nt) eacc[nt] = (fx4){0.f, 0.f, 0.f, 0.f};

    const int cmax = q >> 5;
    for (int c = 0; c <= cmax; ++c) {
        const unsigned short* fb = bfp + ((((b * 32 + 2 * c) * 4) * 64 + lane) << 3);
        sx8 fa0 = *(const sx8*)(fb);
        sx8 fa1 = *(const sx8*)(fb + 512);
        sx8 fa2 = *(const sx8*)(fb + 1024);
        sx8 fa3 = *(const sx8*)(fb + 1536);
        sx8 fb0 = *(const sx8*)(fb + 2048);
        sx8 fb1 = *(const sx8*)(fb + 2560);
        sx8 fb2 = *(const sx8*)(fb + 3072);
        sx8 fb3 = *(const sx8*)(fb + 3584);
        const unsigned short* fe = xep + ((((b * 16 + c) * 4) * 64 + lane) << 3);
        sx8 e0 = *(const sx8*)(fe);
        sx8 e1 = *(const sx8*)(fe + 512);
        sx8 e2 = *(const sx8*)(fe + 1024);
        sx8 e3 = *(const sx8*)(fe + 1536);

        fx4 accA[4], accB[4];
        #pragma unroll
        for (int ht = 0; ht < 4; ++ht) {
            accA[ht] = (fx4){hqr[ht][0], hqr[ht][1], hqr[ht][2], hqr[ht][3]};
            accB[ht] = accA[ht];
        }
        #pragma unroll
        for (int ht = 0; ht < 4; ++ht) {
            accA[ht] = __builtin_amdgcn_mfma_f32_16x16x32_bf16(afrag[ht][0], fa0, accA[ht], 0, 0, 0);
            accB[ht] = __builtin_amdgcn_mfma_f32_16x16x32_bf16(afrag[ht][0], fb0, accB[ht], 0, 0, 0);
        }
        #pragma unroll
        for (int ht = 0; ht < 4; ++ht) {
            accA[ht] = __builtin_amdgcn_mfma_f32_16x16x32_bf16(afrag[ht][1], fa1, accA[ht], 0, 0, 0);
            accB[ht] = __builtin_amdgcn_mfma_f32_16x16x32_bf16(afrag[ht][1], fb1, accB[ht], 0, 0, 0);
        }
        #pragma unroll
        for (int ht = 0; ht < 4; ++ht) {
            accA[ht] = __builtin_amdgcn_mfma_f32_16x16x32_bf16(oh[ht], (ht < 2) ? fa2 : fa3, accA[ht], 0, 0, 0);
            accB[ht] = __builtin_amdgcn_mfma_f32_16x16x32_bf16(oh[ht], (ht < 2) ? fb2 : fb3, accB[ht], 0, 0, 0);
        }

        // PReLU + W2 dot (h split across quads; reduce over quads)
        float s0 = 0.f, s1 = 0.f;
        #pragma unroll
        for (int ht = 0; ht < 4; ++ht)
            #pragma unroll
            for (int r = 0; r < 4; ++r) {
                float za = accA[ht][r];
                float zb = accB[ht][r];
                s0 = fmaf(w2r[ht][r], fmaf(pa, fminf(za, 0.f), fmaxf(za, 0.f)), s0);
                s1 = fmaf(w2r[ht][r], fmaf(pa, fminf(zb, 0.f), fmaxf(zb, 0.f)), s1);
            }
        s0 += __shfl_xor(s0, 16, 64);
        s0 += __shfl_xor(s0, 32, 64);
        s1 += __shfl_xor(s1, 16, 64);
        s1 += __shfl_xor(s1, 32, 64);
        int k0 = c * 32 + n;
        s0 = (k0 <= q)      ? s0 + b2v : 0.f;
        s1 = (k0 + 16 <= q) ? s1 + b2v : 0.f;

        // scores -> A-frag (k-layout) via bpermute of packed bf16 pair
        unsigned packed = (unsigned)f2bf(s0) | ((unsigned)f2bf(s1) << 16);
        int g[8];
        #pragma unroll
        for (int j = 0; j < 8; ++j)
            g[j] = __builtin_amdgcn_ds_bpermute(idxs[j], (int)packed);
        ix4 sw;
        sw[0] = (int)__builtin_amdgcn_perm((unsigned)g[1], (unsigned)g[0], sel);
        sw[1] = (int)__builtin_amdgcn_perm((unsigned)g[3], (unsigned)g[2], sel);
        sw[2] = (int)__builtin_amdgcn_perm((unsigned)g[5], (unsigned)g[4], sel);
        sw[3] = (int)__builtin_amdgcn_perm((unsigned)g[7], (unsigned)g[6], sel);
        sx8 sfrag = __builtin_bit_cast(sx8, sw);

        eacc[0] = __builtin_amdgcn_mfma_f32_16x16x32_bf16(sfrag, e0, eacc[0], 0, 0, 0);
        eacc[1] = __builtin_amdgcn_mfma_f32_16x16x32_bf16(sfrag, e1, eacc[1], 0, 0, 0);
        eacc[2] = __builtin_amdgcn_mfma_f32_16x16x32_bf16(sfrag, e2, eacc[2], 0, 0, 0);
        eacc[3] = __builtin_amdgcn_mfma_f32_16x16x32_bf16(sfrag, e3, eacc[3], 0, 0, 0);
    }

    // all m-rows of eacc are identical; lane stores d = quad*16 + n
    float ov = eacc[0][0];
    if (quad == 1) ov = eacc[1][0];
    if (quad == 2) ov = eacc[2][0];
    if (quad == 3) ov = eacc[3][0];
    out[bq * 64 + quad * 16 + n] = ov;
}

extern "C" void kernel_launch(void* const* d_in, const int* in_sizes, int n_in,
                              void* d_out, int out_size, void* d_ws, size_t ws_size,
                              hipStream_t stream) {
    const float* x   = (const float*)d_in[1];
    const float* vmk = (const float*)d_in[2];
    const float* W1  = (const float*)d_in[3];
    const float* b1  = (const float*)d_in[4];
    const float* pa  = (const float*)d_in[5];
    const float* W2  = (const float*)d_in[6];
    const float* b2  = (const float*)d_in[7];
    float* ws  = (float*)d_ws;
    float* out = (float*)d_out;

    hipLaunchKernelGGL(prep, dim3(NB * NN / 4), dim3(256), 0, stream,
                       x, vmk, W1, b1, ws);
    hipLaunchKernelGGL(k2_main, dim3(NB * NN / 4), dim3(256), 0, stream,
                       x, pa, W2, b2, ws, out);
}

// Round 4
// 121.785 us; speedup vs baseline: 1.5869x; 1.5869x over previous
//
#include <hip/hip_runtime.h>

// DIN encoder. B=8, N=512, D=64, H=64. Two launches:
//   prep   — weight transforms, hq, hk-scatter, X B-frags, enc-X B-frags
//   k2_main— one wave per (b,q), 32 keys/iter, everything through MFMA
// R4: __launch_bounds__(256,2) on k2_main — R3's (256,4) capped VGPR at 64
// and spilled ~30 regs to scratch (138MB FETCH / 54MB WRITE of pure spill
// traffic). 2 blocks/CU matches measured occupancy anyway.
#define NB 8
#define NN 512

// ws layout (float offsets)
#define WS_WMF 0        // Wm A-frag-major fp32 [8 slot][64 lane][8]          4096
#define WS_HQ  4096     // hq fp32 [B*N][64]                                262144
#define WS_BF  266240   // B-frags bf16 [B][32 t][4 c][64 lane][8]   (262144 fl)
#define WS_XE  528384   // enc-X bf16 [B][16 c32][4 nt][64 lane][8]  (131072 fl)
// total 659456 floats = 2.64 MB

typedef float fx4 __attribute__((ext_vector_type(4)));
typedef short sx8 __attribute__((ext_vector_type(8)));
typedef int   ix4 __attribute__((ext_vector_type(4)));

static __device__ inline unsigned short f2bf(float f) {
    unsigned u = __float_as_uint(f);
    return (unsigned short)((u + 0x7FFFu + ((u >> 16) & 1u)) >> 16);  // RNE
}

// ---------------- fused prep ----------------
__global__ __launch_bounds__(256) void prep(const float* __restrict__ x,
                                            const float* __restrict__ vm,
                                            const float* __restrict__ W1,
                                            const float* __restrict__ b1,
                                            float* __restrict__ ws) {
    __shared__ float lwq[64 * 65];   // (Wq+Wd)^T  [d][h], pad 65
    __shared__ float lwk[64 * 65];   // (Wk-Wd)^T
    __shared__ float xs[256];
    const int t = threadIdx.x;
    const int blk = blockIdx.x;

    // stage weight combos, coalesced over d
    {
        int d = t & 63, hb = t >> 6;
        #pragma unroll 4
        for (int i = 0; i < 16; ++i) {
            int h = i * 4 + hb;
            float a = W1[h * 256 + d];
            float bb = W1[h * 256 + 64 + d];
            float c = W1[h * 256 + 128 + d];
            lwq[d * 65 + h] = a + c;
            lwk[d * 65 + h] = bb - c;
        }
    }
    const int r0 = blk * 4;
    xs[t] = x[r0 * 64 + t];
    __syncthreads();

    // hq + hk for this block's 4 rows
    {
        int r = t >> 6, h = t & 63;
        const float* xr = xs + r * 64;
        float aq = b1[h], ak = 0.f;
        #pragma unroll
        for (int dd = 0; dd < 64; ++dd) {
            float xv = xr[dd];
            aq = fmaf(xv, lwq[dd * 65 + h], aq);
            ak = fmaf(xv, lwk[dd * 65 + h], ak);
        }
        int row = r0 + r;
        (ws + WS_HQ)[row * 64 + h] = aq;
        // scatter hk into B-frag chunk c=2+(h>>5)
        unsigned short* bfp = (unsigned short*)(ws + WS_BF);
        int bb = row >> 9, k = row & 511;
        int tt = k >> 4, nn = k & 15;
        int c = 2 + (h >> 5);
        int qd = (h >> 3) & 3, j = h & 7;
        int ln = qd * 16 + nn;
        bfp[((((bb * 32 + tt) * 4 + c) * 64 + ln) << 3) + j] = f2bf(ak);
    }

    if (blk < 256) {
        int b = blk >> 5, t5 = blk & 31;
        // X -> BF chunks 0/1
        if (t < 128) {
            unsigned short* bfp = (unsigned short*)(ws + WS_BF);
            int c = t >> 6, L = t & 63;
            int nn = L & 15, qd = L >> 4;
            const float* src = x + ((b * 512 + t5 * 16 + nn) * 64 + c * 32 + qd * 8);
            fx4 v0 = *(const fx4*)src;
            fx4 v1 = *(const fx4*)(src + 4);
            uint4 o;
            o.x = (unsigned)f2bf(v0[0]) | ((unsigned)f2bf(v0[1]) << 16);
            o.y = (unsigned)f2bf(v0[2]) | ((unsigned)f2bf(v0[3]) << 16);
            o.z = (unsigned)f2bf(v1[0]) | ((unsigned)f2bf(v1[1]) << 16);
            o.w = (unsigned)f2bf(v1[2]) | ((unsigned)f2bf(v1[3]) << 16);
            *(uint4*)(bfp + ((((b * 32 + t5) * 4 + c) * 64 + L) << 3)) = o;
        }
        // masked X -> enc B-frags (XE)
        {
            unsigned short* xep = (unsigned short*)(ws + WS_XE);
            int c32 = t5 >> 1, half = t5 & 1;
            int nt = t >> 6, r = t & 63;
            int L = half * 32 + (r & 31);
            int j0 = (r >> 5) * 4;
            int quad = L >> 4, nn = L & 15;
            unsigned short u[4];
            #pragma unroll
            for (int i = 0; i < 4; ++i) {
                int key = c32 * 32 + quad * 8 + j0 + i;
                float v = x[(b * 512 + key) * 64 + nt * 16 + nn] * vm[b * 512 + key];
                u[i] = f2bf(v);
            }
            uint2 o;
            o.x = (unsigned)u[0] | ((unsigned)u[1] << 16);
            o.y = (unsigned)u[2] | ((unsigned)u[3] << 16);
            *(uint2*)(xep + (((((b * 16 + c32) * 4 + nt) * 64 + L) << 3) + j0)) = o;
        }
    } else if (blk < 258) {
        // Wm A-fragment-major
        float* wmf = ws + WS_WMF;
        int e = (blk - 256) * 256 + t;       // 0..511
        int slot = e >> 6, lane = e & 63;
        int ht = slot >> 1, hf = slot & 1;
        int m = lane & 15, qd = lane >> 4;
        int h = ht * 16 + m;
        int dbase = hf * 32 + qd * 8;
        #pragma unroll
        for (int j = 0; j < 8; ++j)
            wmf[e * 8 + j] = W1[h * 256 + 192 + dbase + j];
    }
}

// ---------------- main ----------------
__global__ __launch_bounds__(256, 2) void k2_main(const float* __restrict__ x,
                                                  const float* __restrict__ prelu_a,
                                                  const float* __restrict__ W2,
                                                  const float* __restrict__ b2,
                                                  const float* __restrict__ ws,
                                                  float* __restrict__ out) {
    const int tid  = threadIdx.x;
    const int lane = tid & 63;
    const int wid  = blockIdx.x * 4 + (tid >> 6);
    const int b    = wid >> 9;
    const int rr   = wid & 511;
    const int q    = (rr & 1) ? (511 - (rr >> 1)) : (rr >> 1);  // balance
    const int n    = lane & 15, quad = lane >> 4;
    const int bq   = b * 512 + q;

    const float* wmf = ws + WS_WMF;
    const float* hq  = ws + WS_HQ;
    const unsigned short* bfp = (const unsigned short*)(ws + WS_BF);
    const unsigned short* xep = (const unsigned short*)(ws + WS_XE);

    const float pa  = prelu_a[0];
    const float b2v = b2[0];

    // hq (acc init) and W2 registers: h = ht*16 + quad*4 + r
    float hqr[4][4], w2r[4][4];
    #pragma unroll
    for (int ht = 0; ht < 4; ++ht) {
        fx4 vh = *(const fx4*)(hq + bq * 64 + ht * 16 + quad * 4);
        fx4 vw = *(const fx4*)(W2 + ht * 16 + quad * 4);
        #pragma unroll
        for (int r = 0; r < 4; ++r) { hqr[ht][r] = vh[r]; w2r[ht][r] = vw[r]; }
    }

    // xq for A-frags: lane needs d = half*32 + quad*8 + j
    float xq[2][8];
    {
        const float* xp = x + bq * 64 + quad * 8;
        fx4 t0 = *(const fx4*)xp;
        fx4 t1 = *(const fx4*)(xp + 4);
        fx4 t2 = *(const fx4*)(xp + 32);
        fx4 t3 = *(const fx4*)(xp + 36);
        #pragma unroll
        for (int j = 0; j < 4; ++j) {
            xq[0][j] = t0[j]; xq[0][4 + j] = t1[j];
            xq[1][j] = t2[j]; xq[1][4 + j] = t3[j];
        }
    }

    // A-frags: Wm ⊙ xq (bf16)
    sx8 afrag[4][2];
    #pragma unroll
    for (int ht = 0; ht < 4; ++ht)
        #pragma unroll
        for (int hf = 0; hf < 2; ++hf) {
            const float* wp = wmf + (((ht * 2 + hf) * 64 + lane) << 3);
            fx4 w0 = *(const fx4*)wp;
            fx4 w1 = *(const fx4*)(wp + 4);
            sx8 a;
            #pragma unroll
            for (int j = 0; j < 4; ++j) {
                a[j]     = (short)f2bf(w0[j] * xq[hf][j]);
                a[4 + j] = (short)f2bf(w1[j] * xq[hf][4 + j]);
            }
            afrag[ht][hf] = a;
        }

    // one-hot A-frags for the hk fold
    sx8 oh[4];
    #pragma unroll
    for (int ht = 0; ht < 4; ++ht) {
        sx8 a;
        #pragma unroll
        for (int j = 0; j < 8; ++j) {
            int hp = (ht >> 1) * 32 + quad * 8 + j;
            a[j] = (hp == ht * 16 + n) ? (short)0x3F80 : (short)0;
        }
        oh[ht] = a;
    }

    // score -> A-frag gather constants
    int idxs[8];
    #pragma unroll
    for (int j = 0; j < 8; ++j) idxs[j] = ((quad * 8 + j) & 15) << 2;
    const unsigned sel = (quad < 2) ? 0x05040100u : 0x07060302u;

    fx4 eacc[4];
    #pragma unroll
    for (int nt = 0; nt < 4; ++nt) eacc[nt] = (fx4){0.f, 0.f, 0.f, 0.f};

    const int cmax = q >> 5;
    for (int c = 0; c <= cmax; ++c) {
        const unsigned short* fb = bfp + ((((b * 32 + 2 * c) * 4) * 64 + lane) << 3);
        sx8 fa0 = *(const sx8*)(fb);
        sx8 fa1 = *(const sx8*)(fb + 512);
        sx8 fa2 = *(const sx8*)(fb + 1024);
        sx8 fa3 = *(const sx8*)(fb + 1536);
        sx8 fb0 = *(const sx8*)(fb + 2048);
        sx8 fb1 = *(const sx8*)(fb + 2560);
        sx8 fb2 = *(const sx8*)(fb + 3072);
        sx8 fb3 = *(const sx8*)(fb + 3584);
        const unsigned short* fe = xep + ((((b * 16 + c) * 4) * 64 + lane) << 3);
        sx8 e0 = *(const sx8*)(fe);
        sx8 e1 = *(const sx8*)(fe + 512);
        sx8 e2 = *(const sx8*)(fe + 1024);
        sx8 e3 = *(const sx8*)(fe + 1536);

        fx4 accA[4], accB[4];
        #pragma unroll
        for (int ht = 0; ht < 4; ++ht) {
            accA[ht] = (fx4){hqr[ht][0], hqr[ht][1], hqr[ht][2], hqr[ht][3]};
            accB[ht] = accA[ht];
        }
        #pragma unroll
        for (int ht = 0; ht < 4; ++ht) {
            accA[ht] = __builtin_amdgcn_mfma_f32_16x16x32_bf16(afrag[ht][0], fa0, accA[ht], 0, 0, 0);
            accB[ht] = __builtin_amdgcn_mfma_f32_16x16x32_bf16(afrag[ht][0], fb0, accB[ht], 0, 0, 0);
        }
        #pragma unroll
        for (int ht = 0; ht < 4; ++ht) {
            accA[ht] = __builtin_amdgcn_mfma_f32_16x16x32_bf16(afrag[ht][1], fa1, accA[ht], 0, 0, 0);
            accB[ht] = __builtin_amdgcn_mfma_f32_16x16x32_bf16(afrag[ht][1], fb1, accB[ht], 0, 0, 0);
        }
        #pragma unroll
        for (int ht = 0; ht < 4; ++ht) {
            accA[ht] = __builtin_amdgcn_mfma_f32_16x16x32_bf16(oh[ht], (ht < 2) ? fa2 : fa3, accA[ht], 0, 0, 0);
            accB[ht] = __builtin_amdgcn_mfma_f32_16x16x32_bf16(oh[ht], (ht < 2) ? fb2 : fb3, accB[ht], 0, 0, 0);
        }

        // PReLU + W2 dot (h split across quads; reduce over quads)
        float s0 = 0.f, s1 = 0.f;
        #pragma unroll
        for (int ht = 0; ht < 4; ++ht)
            #pragma unroll
            for (int r = 0; r < 4; ++r) {
                float za = accA[ht][r];
                float zb = accB[ht][r];
                s0 = fmaf(w2r[ht][r], fmaf(pa, fminf(za, 0.f), fmaxf(za, 0.f)), s0);
                s1 = fmaf(w2r[ht][r], fmaf(pa, fminf(zb, 0.f), fmaxf(zb, 0.f)), s1);
            }
        s0 += __shfl_xor(s0, 16, 64);
        s0 += __shfl_xor(s0, 32, 64);
        s1 += __shfl_xor(s1, 16, 64);
        s1 += __shfl_xor(s1, 32, 64);
        int k0 = c * 32 + n;
        s0 = (k0 <= q)      ? s0 + b2v : 0.f;
        s1 = (k0 + 16 <= q) ? s1 + b2v : 0.f;

        // scores -> A-frag (k-layout) via bpermute of packed bf16 pair
        unsigned packed = (unsigned)f2bf(s0) | ((unsigned)f2bf(s1) << 16);
        int g[8];
        #pragma unroll
        for (int j = 0; j < 8; ++j)
            g[j] = __builtin_amdgcn_ds_bpermute(idxs[j], (int)packed);
        ix4 sw;
        sw[0] = (int)__builtin_amdgcn_perm((unsigned)g[1], (unsigned)g[0], sel);
        sw[1] = (int)__builtin_amdgcn_perm((unsigned)g[3], (unsigned)g[2], sel);
        sw[2] = (int)__builtin_amdgcn_perm((unsigned)g[5], (unsigned)g[4], sel);
        sw[3] = (int)__builtin_amdgcn_perm((unsigned)g[7], (unsigned)g[6], sel);
        sx8 sfrag = __builtin_bit_cast(sx8, sw);

        eacc[0] = __builtin_amdgcn_mfma_f32_16x16x32_bf16(sfrag, e0, eacc[0], 0, 0, 0);
        eacc[1] = __builtin_amdgcn_mfma_f32_16x16x32_bf16(sfrag, e1, eacc[1], 0, 0, 0);
        eacc[2] = __builtin_amdgcn_mfma_f32_16x16x32_bf16(sfrag, e2, eacc[2], 0, 0, 0);
        eacc[3] = __builtin_amdgcn_mfma_f32_16x16x32_bf16(sfrag, e3, eacc[3], 0, 0, 0);
    }

    // all m-rows of eacc are identical; lane stores d = quad*16 + n
    float ov = eacc[0][0];
    if (quad == 1) ov = eacc[1][0];
    if (quad == 2) ov = eacc[2][0];
    if (quad == 3) ov = eacc[3][0];
    out[bq * 64 + quad * 16 + n] = ov;
}

extern "C" void kernel_launch(void* const* d_in, const int* in_sizes, int n_in,
                              void* d_out, int out_size, void* d_ws, size_t ws_size,
                              hipStream_t stream) {
    const float* x   = (const float*)d_in[1];
    const float* vmk = (const float*)d_in[2];
    const float* W1  = (const float*)d_in[3];
    const float* b1  = (const float*)d_in[4];
    const float* pa  = (const float*)d_in[5];
    const float* W2  = (const float*)d_in[6];
    const float* b2  = (const float*)d_in[7];
    float* ws  = (float*)d_ws;
    float* out = (float*)d_out;

    hipLaunchKernelGGL(prep, dim3(NB * NN / 4), dim3(256), 0, stream,
                       x, vmk, W1, b1, ws);
    hipLaunchKernelGGL(k2_main, dim3(NB * NN / 4), dim3(256), 0, stream,
                       x, pa, W2, b2, ws, out);
}